// Round 8
// baseline (127.103 us; speedup 1.0000x reference)
//
#include <hip/hip_runtime.h>
#include <hip/hip_bf16.h>
#include <stdint.h>

typedef __attribute__((ext_vector_type(8))) __bf16 bf16x8;
typedef __attribute__((ext_vector_type(4))) float f32x4;

constexpr int Bn = 4096;   // batch
constexpr int Dd = 1024;   // feature dim
constexpr int Cc = 1000;   // classes
constexpr int PANEL_ELEMS = 128 * Dd;   // elems per 128-row panel of xnt
constexpr int NKT = Dd / 32;            // 32 K-steps of BK=32

__device__ __forceinline__ float wsum(float v) {
#pragma unroll
  for (int m = 32; m >= 1; m >>= 1) v += __shfl_xor(v, m);
  return v;
}
__device__ __forceinline__ float wmax(float v) {
#pragma unroll
  for (int m = 32; m >= 1; m >>= 1) v = fmaxf(v, __shfl_xor(v, m));
  return v;
}

// ---- fused: normalize -> blocked-bf16 xnt | CE rows | first-occurrence scan ----
// Blocked layout: elem (row r, k) at (r>>7)*131072 + (k>>5)*4096 + ((k>>3)&3)*1024 + (r&127)*8 + (k&7)
__global__ void prep_kernel(const float* __restrict__ data, const float* __restrict__ x,
                            const int* __restrict__ y, unsigned short* __restrict__ xnt,
                            float* __restrict__ celogp, float* __restrict__ total,
                            int* __restrict__ first_occ) {
  __shared__ float red[4];
  __shared__ float red2[4];
  __shared__ int fo[Cc];
  int b = blockIdx.x;
  int t = threadIdx.x;
  if (b < Bn) {
    if (t == 0) total[b] = 0.0f;
    const float4* xr = (const float4*)(x + (size_t)b * Dd);
    float4 v = xr[t];                       // 256 threads * 4 floats
    float ss = v.x * v.x + v.y * v.y + v.z * v.z + v.w * v.w;
    ss = wsum(ss);
    if ((t & 63) == 0) red[t >> 6] = ss;
    __syncthreads();
    float inv = 1.0f / fmaxf(sqrtf(red[0] + red[1] + red[2] + red[3]), 1e-8f);
    float f[4] = {v.x * inv, v.y * inv, v.z * inv, v.w * inv};
    ushort4 o;
    unsigned short* op = (unsigned short*)&o;
#pragma unroll
    for (int k = 0; k < 4; k++) {          // f32 -> bf16 RNE
      unsigned u = __float_as_uint(f[k]);
      u += 0x7fffu + ((u >> 16) & 1u);
      op[k] = (unsigned short)(u >> 16);
    }
    int p = b >> 7, rl = b & 127;
    int d = t * 4;                          // global k of first elem
    int kt = d >> 5, kg = (d >> 3) & 3, e = d & 7;  // e in {0,4}
    *(ushort4*)(xnt + (size_t)p * PANEL_ELEMS + kt * 4096 + kg * 1024 + rl * 8 + e) = o;
  } else if (b < 2 * Bn) {
    int i = b - Bn;
    const float* row = data + (size_t)i * Cc;
    float m = -1e30f;
    for (int c = t; c < Cc; c += 256) m = fmaxf(m, row[c]);
    m = wmax(m);
    if ((t & 63) == 0) red[t >> 6] = m;
    __syncthreads();
    m = fmaxf(fmaxf(red[0], red[1]), fmaxf(red[2], red[3]));
    float s = 0.f;
    for (int c = t; c < Cc; c += 256) s += __expf(row[c] - m);
    s = wsum(s);
    if ((t & 63) == 0) red2[t >> 6] = s;
    __syncthreads();
    if (t == 0) {
      float tot = red2[0] + red2[1] + red2[2] + red2[3];
      celogp[i] = -(row[y[i]] - m - logf(tot));
    }
  } else {
    for (int c = t; c < Cc; c += 256) fo[c] = 0x7fffffff;
    __syncthreads();
    for (int i = t; i < Bn; i += 256) atomicMin(&fo[y[i]], i);
    __syncthreads();
    for (int c = t; c < Cc; c += 256) first_occ[c] = fo[c];
  }
}

// ---- barrier-free streaming GEMM: S-rows = A-band(LDS) x B(streamed from L2) ----
// 256 blocks (1/CU): block = (row-band 64) x (col-quarter 1024). 8 waves x 128 cols.
// A-band 64x1024 bf16 = 128KB LDS, loaded once (one barrier). Main loop: ZERO barriers;
// B fragments register-double-buffered from global (xnt cached: per-XCD col-slice 2MB
// fits 4MB L2 since q = blockIdx&3 is constant per XCD residue class).
// Epilogue: total[r] += sum_c exp(2*S[r,c]) ; posdot[c] = S[jstar[c], c].
__global__ __launch_bounds__(512, 2) void gemm_stream_kernel(
    const __bf16* __restrict__ xnt, const int* __restrict__ y,
    const int* __restrict__ first_occ, float* __restrict__ total,
    float* __restrict__ posdot) {
  __shared__ __align__(16) __bf16 As[128 * 512];   // [kt32][kg4][row64][e8] = 128KB
  int t = threadIdx.x, lane = t & 63, w = t >> 6;  // 8 waves
  int band = blockIdx.x >> 2, q = blockIdx.x & 3;
  int kg = lane >> 4, fr = lane & 15;

  // ---- stage A-band once: 128 chunks of 1KB, wave w takes chunk issue*8+w ----
  const __bf16* pA = xnt + (size_t)(band >> 1) * PANEL_ELEMS + (band & 1) * 512;
#pragma unroll
  for (int issue = 0; issue < 16; ++issue) {
    int g = issue * 8 + w;                 // chunk id = kt*4+kg
    const __bf16* src = pA + (g >> 2) * 4096 + (g & 3) * 1024 + lane * 8;
    __builtin_amdgcn_global_load_lds((const __attribute__((address_space(1))) void*)src,
                                     (__attribute__((address_space(3))) void*)&As[g * 512],
                                     16, 0, 0);
  }

  // ---- B base for this wave: cols c0 + [0,128) live in one 128-col panel ----
  const __bf16* bB = xnt + (size_t)(q * 8 + w) * PANEL_ELEMS + kg * 1024 + fr * 8;
  bf16x8 bc[8], bn[8];
#pragma unroll
  for (int nj = 0; nj < 8; ++nj) bc[nj] = *(const bf16x8*)(bB + nj * 128);  // kt=0

  f32x4 acc[4][8] = {};
  __syncthreads();   // A-band staged (drains vmcnt); the ONLY barrier

  // ---- main loop: 32 K-steps, no barriers ----
#pragma unroll 2
  for (int kt = 0; kt < NKT; ++kt) {
    int ktn = (kt + 1 < NKT) ? kt + 1 : 0;          // harmless re-read on last iter
#pragma unroll
    for (int nj = 0; nj < 8; ++nj) bn[nj] = *(const bf16x8*)(bB + ktn * 4096 + nj * 128);
    const bf16x8* Ap = (const bf16x8*)&As[kt * 2048 + kg * 512 + fr * 8];
    bf16x8 af[4];
#pragma unroll
    for (int mi = 0; mi < 4; ++mi) af[mi] = Ap[mi * 16];   // rows mi*16+fr
#pragma unroll
    for (int mi = 0; mi < 4; ++mi)
#pragma unroll
      for (int nj = 0; nj < 8; ++nj)
        acc[mi][nj] = __builtin_amdgcn_mfma_f32_16x16x32_bf16(af[mi], bc[nj], acc[mi][nj], 0, 0, 0);
#pragma unroll
    for (int nj = 0; nj < 8; ++nj) bc[nj] = bn[nj];
  }

  // ---- epilogue: exp(2s) = exp2(s * 2*log2(e)); row-sums + posdot ----
  const float c2 = 2.885390081777927f;
  int rgrp = lane >> 4, cl = lane & 15;
  int c0 = q * 1024 + w * 128;
  int cidx[8], jst[8];
#pragma unroll
  for (int nj = 0; nj < 8; ++nj) {
    cidx[nj] = c0 + nj * 16 + cl;
    jst[nj] = first_occ[y[cidx[nj]]];
  }
#pragma unroll
  for (int mi = 0; mi < 4; ++mi) {
    int rb = band * 64 + mi * 16 + rgrp * 4;
#pragma unroll
    for (int reg = 0; reg < 4; ++reg) {
      int r = rb + reg;
      float rs = 0.f;
#pragma unroll
      for (int nj = 0; nj < 8; ++nj) {
        float v = acc[mi][nj][reg];
        rs += exp2f(v * c2);
        if (jst[nj] == r) posdot[cidx[nj]] = v;   // unique (r,c) globally
      }
#pragma unroll
      for (int m = 1; m <= 8; m <<= 1) rs += __shfl_xor(rs, m);  // over 16 col-lanes
      if (cl == 0) atomicAdd(&total[r], rs);
    }
  }
}

// ---- final reduction ----
__global__ void finalize_kernel(const float* __restrict__ total, const float* __restrict__ posdot,
                                const float* __restrict__ celogp, float* __restrict__ out) {
  int t = threadIdx.x;  // 1024 threads
  float fs = 0.f, cs = 0.f;
  for (int i = t; i < Bn; i += 1024) {
    fs += logf(total[i]) - 2.0f * posdot[i];
    cs += celogp[i];
  }
  fs = wsum(fs);
  cs = wsum(cs);
  __shared__ float rf[16], rc[16];
  if ((t & 63) == 0) { rf[t >> 6] = fs; rc[t >> 6] = cs; }
  __syncthreads();
  if (t == 0) {
    float lf = 0.f, la = 0.f;
#pragma unroll
    for (int w = 0; w < 16; w++) { lf += rf[w]; la += rc[w]; }
    lf /= (float)Bn;
    la /= (float)Bn;
    out[0] = la + 0.05f * lf;
    out[1] = la;
    out[2] = lf;
  }
}

extern "C" void kernel_launch(void* const* d_in, const int* in_sizes, int n_in,
                              void* d_out, int out_size, void* d_ws, size_t ws_size,
                              hipStream_t stream) {
  const float* data = (const float*)d_in[0];
  const float* x = (const float*)d_in[1];
  const int* y = (const int*)d_in[2];
  char* ws = (char*)d_ws;
  unsigned short* xn = (unsigned short*)ws;                       // 8 MB bf16, blocked layout
  float* total = (float*)(ws + (size_t)8 * 1024 * 1024);          // 16 KB
  float* posdot = total + Bn;                                     // 16 KB
  float* celogp = posdot + Bn;                                    // 16 KB
  int* first_occ = (int*)(celogp + Bn);                           // 4 KB
  float* out = (float*)d_out;

  hipLaunchKernelGGL(prep_kernel, dim3(2 * Bn + 1), dim3(256), 0, stream,
                     data, x, y, xn, celogp, total, first_occ);
  hipLaunchKernelGGL(gemm_stream_kernel, dim3(256), dim3(512), 0, stream,
                     (const __bf16*)xn, y, first_occ, total, posdot);
  hipLaunchKernelGGL(finalize_kernel, dim3(1), dim3(1024), 0, stream, total, posdot, celogp, out);
}